// Round 1
// baseline (1533.001 us; speedup 1.0000x reference)
//
#include <hip/hip_runtime.h>
#include <hip/hip_bf16.h>

#define BB 4
#define CC 64
#define NN 4096
#define HH 64
#define AH 256
#define KNN 16
#define EPSV 1e-5f

// ---------------------------------------------------------------------------
// Kernel 1: fold BN params, transpose P2 (C,H)->(H,C) and A2 (C,AH)->(AH,C)
// ---------------------------------------------------------------------------
__global__ void prep_params(const float* __restrict__ P2, const float* __restrict__ A2,
                            const float* __restrict__ g1, const float* __restrict__ b1,
                            const float* __restrict__ m1, const float* __restrict__ v1,
                            const float* __restrict__ g2, const float* __restrict__ b2,
                            const float* __restrict__ m2, const float* __restrict__ v2,
                            float* __restrict__ P2T, float* __restrict__ A2T,
                            float* __restrict__ bn1s, float* __restrict__ bn1c,
                            float* __restrict__ bn2s, float* __restrict__ bn2c) {
    int t = threadIdx.x;
    if (t < HH) {
        float s = g1[t] * rsqrtf(v1[t] + EPSV);
        bn1s[t] = s;
        bn1c[t] = b1[t] - m1[t] * s;
    }
    if (t < AH) {
        float s = g2[t] * rsqrtf(v2[t] + EPSV);
        bn2s[t] = s;
        bn2c[t] = b2[t] - m2[t] * s;
    }
    for (int i = t; i < HH * CC; i += 256) {
        int h = i >> 6, c = i & 63;
        P2T[i] = P2[c * HH + h];
    }
    for (int i = t; i < AH * CC; i += 256) {
        int h = i >> 6, o = i & 63;
        A2T[i] = A2[o * AH + h];
    }
}

// ---------------------------------------------------------------------------
// Kernel 2: y1 = Ws*y+bs, key = Wk*y1+bk, query = Wq*x+bq  (point-major out)
// ---------------------------------------------------------------------------
__global__ void prep_features(const float* __restrict__ x, const float* __restrict__ y,
                              const float* __restrict__ Ws, const float* __restrict__ bs,
                              const float* __restrict__ Wk, const float* __restrict__ bk,
                              const float* __restrict__ Wq, const float* __restrict__ bq,
                              float* __restrict__ y1_t, float* __restrict__ key_t,
                              float* __restrict__ qry_t) {
    int gid = blockIdx.x * blockDim.x + threadIdx.x;  // 0..B*N-1
    int b = gid >> 12;
    int n = gid & (NN - 1);

    float yv[CC];
#pragma unroll
    for (int c = 0; c < CC; ++c) yv[c] = y[((size_t)(b * CC + c)) * NN + n];

    float y1v[CC];
#pragma unroll 4
    for (int o = 0; o < CC; ++o) {
        const float* wr = Ws + o * CC;
        float s0 = 0.f, s1 = 0.f, s2 = 0.f, s3 = 0.f;
#pragma unroll
        for (int d = 0; d < 16; ++d) {
            s0 += wr[4 * d + 0] * yv[4 * d + 0];
            s1 += wr[4 * d + 1] * yv[4 * d + 1];
            s2 += wr[4 * d + 2] * yv[4 * d + 2];
            s3 += wr[4 * d + 3] * yv[4 * d + 3];
        }
        y1v[o] = (s0 + s1) + (s2 + s3) + bs[o];
    }

    float* y1o = y1_t + (size_t)gid * CC;
#pragma unroll
    for (int o = 0; o < CC; ++o) y1o[o] = y1v[o];

    float* ko = key_t + (size_t)gid * CC;
#pragma unroll 4
    for (int o = 0; o < CC; ++o) {
        const float* wr = Wk + o * CC;
        float s0 = 0.f, s1 = 0.f, s2 = 0.f, s3 = 0.f;
#pragma unroll
        for (int d = 0; d < 16; ++d) {
            s0 += wr[4 * d + 0] * y1v[4 * d + 0];
            s1 += wr[4 * d + 1] * y1v[4 * d + 1];
            s2 += wr[4 * d + 2] * y1v[4 * d + 2];
            s3 += wr[4 * d + 3] * y1v[4 * d + 3];
        }
        ko[o] = (s0 + s1) + (s2 + s3) + bk[o];
    }

    float x0 = x[(size_t)(b * 3 + 0) * NN + n];
    float x1 = x[(size_t)(b * 3 + 1) * NN + n];
    float x2 = x[(size_t)(b * 3 + 2) * NN + n];
    float* qo = qry_t + (size_t)gid * CC;
#pragma unroll
    for (int o = 0; o < CC; ++o)
        qo[o] = Wq[o * 3 + 0] * x0 + Wq[o * 3 + 1] * x1 + Wq[o * 3 + 2] * x2 + bq[o];
}

// ---------------------------------------------------------------------------
// Kernel 3: exact KNN (top-16 incl. self). One wave per 64 query points;
// whole batch point cloud staged in LDS (48 KB). Replace-max top-16 in regs.
// ---------------------------------------------------------------------------
__global__ void knn_kernel(const float* __restrict__ x, int* __restrict__ idx_out) {
    __shared__ __align__(16) float px[NN];
    __shared__ __align__(16) float py[NN];
    __shared__ __align__(16) float pz[NN];
    int b = blockIdx.x >> 6;                       // 64 blocks per batch
    int n = ((blockIdx.x & 63) << 6) + threadIdx.x;
    const float* xb = x + (size_t)b * 3 * NN;
    for (int t = threadIdx.x; t < NN; t += 64) {
        px[t] = xb[t];
        py[t] = xb[NN + t];
        pz[t] = xb[2 * NN + t];
    }
    __syncthreads();
    float qx = px[n], qy = py[n], qz = pz[n];

    float dist[KNN];
    int nbr[KNN];
#pragma unroll
    for (int s = 0; s < KNN; ++s) { dist[s] = 3.0e38f; nbr[s] = n; }
    float dmax = 3.0e38f;
    int maxslot = 0;

    for (int j0 = 0; j0 < NN; j0 += 4) {
        float4 cx = *(const float4*)(px + j0);
        float4 cy = *(const float4*)(py + j0);
        float4 cz = *(const float4*)(pz + j0);
        float dd[4];
        {
            float ax, ay, az;
            ax = qx - cx.x; ay = qy - cy.x; az = qz - cz.x; dd[0] = ax * ax + ay * ay + az * az;
            ax = qx - cx.y; ay = qy - cy.y; az = qz - cz.y; dd[1] = ax * ax + ay * ay + az * az;
            ax = qx - cx.z; ay = qy - cy.z; az = qz - cz.z; dd[2] = ax * ax + ay * ay + az * az;
            ax = qx - cx.w; ay = qy - cy.w; az = qz - cz.w; dd[3] = ax * ax + ay * ay + az * az;
        }
#pragma unroll
        for (int e = 0; e < 4; ++e) {
            float d = dd[e];
            if (d < dmax) {
                int j = j0 + e;
#pragma unroll
                for (int s = 0; s < KNN; ++s)
                    if (s == maxslot) { dist[s] = d; nbr[s] = j; }
                dmax = dist[0]; maxslot = 0;
#pragma unroll
                for (int s = 1; s < KNN; ++s)
                    if (dist[s] > dmax) { dmax = dist[s]; maxslot = s; }
            }
        }
    }
    int* o = idx_out + ((size_t)b * NN + n) * KNN;
#pragma unroll
    for (int s = 0; s < KNN; ++s) o[s] = nbr[s];
}

// ---------------------------------------------------------------------------
// Kernel 4: fused attention. One thread per (point, neighbor) pair.
// 16 points x 16 neighbors per 256-thread block. Softmax/agg via shfl_xor
// across the 16 lanes of a point (all within one wave).
// ---------------------------------------------------------------------------
__global__ __launch_bounds__(256, 2) void attn_kernel(
    const float* __restrict__ x, const float* __restrict__ y,
    const float* __restrict__ y1_t, const float* __restrict__ key_t,
    const float* __restrict__ qry_t, const int* __restrict__ idx,
    const float* __restrict__ P1, const float* __restrict__ pb1,
    const float* __restrict__ bn1s, const float* __restrict__ bn1c,
    const float* __restrict__ P2T, const float* __restrict__ pb2,
    const float* __restrict__ A1, const float* __restrict__ ab1,
    const float* __restrict__ bn2s, const float* __restrict__ bn2c,
    const float* __restrict__ A2T, const float* __restrict__ ab2,
    const float* __restrict__ Wend, const float* __restrict__ bend,
    float* __restrict__ out) {
    int b = blockIdx.x >> 8;
    int n0 = (blockIdx.x & 255) << 4;
    int t = threadIdx.x;
    int p = t >> 4, k = t & 15;
    int n = n0 + p;
    size_t bn = (size_t)b * NN + n;
    int j = idx[bn * KNN + k];
    size_t bj = (size_t)b * NN + j;

    float dx = x[(size_t)(b * 3 + 0) * NN + n] - x[(size_t)(b * 3 + 0) * NN + j];
    float dy = x[(size_t)(b * 3 + 1) * NN + n] - x[(size_t)(b * 3 + 1) * NN + j];
    float dz = x[(size_t)(b * 3 + 2) * NN + n] - x[(size_t)(b * 3 + 2) * NN + j];

    // u = query - key_gathered
    float u[CC];
    {
        const float4* q4 = (const float4*)(qry_t + bn * CC);
        const float4* k4 = (const float4*)(key_t + bj * CC);
#pragma unroll
        for (int c = 0; c < 16; ++c) {
            float4 q = q4[c], kk = k4[c];
            u[4 * c + 0] = q.x - kk.x;
            u[4 * c + 1] = q.y - kk.y;
            u[4 * c + 2] = q.z - kk.z;
            u[4 * c + 3] = q.w - kk.w;
        }
    }

    // pe = P2 * relu(bn1(P1 * pos_rel + pb1)) + pb2
    float pe[CC];
#pragma unroll
    for (int c = 0; c < CC; ++c) pe[c] = pb2[c];
#pragma unroll 1
    for (int h = 0; h < HH; ++h) {
        float tp = P1[h * 3 + 0] * dx + P1[h * 3 + 1] * dy + P1[h * 3 + 2] * dz + pb1[h];
        float a = fmaxf(tp * bn1s[h] + bn1c[h], 0.f);
        const float* p2r = P2T + h * CC;
#pragma unroll
        for (int c = 0; c < CC; ++c) pe[c] += p2r[c] * a;
    }
#pragma unroll
    for (int c = 0; c < CC; ++c) u[c] += pe[c];

    // attn logits = A2 * relu(bn2(A1*u + ab1)) + ab2
    float acc[CC];
#pragma unroll
    for (int c = 0; c < CC; ++c) acc[c] = ab2[c];
#pragma unroll 1
    for (int h = 0; h < AH; ++h) {
        const float* a1r = A1 + h * CC;
        float s0 = 0.f, s1 = 0.f, s2 = 0.f, s3 = 0.f;
#pragma unroll
        for (int d = 0; d < 16; ++d) {
            s0 += a1r[4 * d + 0] * u[4 * d + 0];
            s1 += a1r[4 * d + 1] * u[4 * d + 1];
            s2 += a1r[4 * d + 2] * u[4 * d + 2];
            s3 += a1r[4 * d + 3] * u[4 * d + 3];
        }
        float sv = (s0 + s1) + (s2 + s3) + ab1[h];
        float hh = fmaxf(sv * bn2s[h] + bn2c[h], 0.f);
        const float* a2r = A2T + h * CC;
#pragma unroll
        for (int c = 0; c < CC; ++c) acc[c] += a2r[c] * hh;
    }

    // softmax over the 16 neighbor lanes per channel, then weighted agg
    const float4* v4 = (const float4*)(y1_t + bn * CC);
    float agg[CC];
#pragma unroll
    for (int c4 = 0; c4 < 16; ++c4) {
        float4 vv = v4[c4];
        float vvv[4] = {vv.x, vv.y, vv.z, vv.w};
#pragma unroll
        for (int e = 0; e < 4; ++e) {
            int c = 4 * c4 + e;
            float v = acc[c];
            float m = v;
            m = fmaxf(m, __shfl_xor(m, 1));
            m = fmaxf(m, __shfl_xor(m, 2));
            m = fmaxf(m, __shfl_xor(m, 4));
            m = fmaxf(m, __shfl_xor(m, 8));
            float ee = __expf(v - m);
            float ssum = ee;
            ssum += __shfl_xor(ssum, 1);
            ssum += __shfl_xor(ssum, 2);
            ssum += __shfl_xor(ssum, 4);
            ssum += __shfl_xor(ssum, 8);
            float w = ee / ssum;
            float contrib = w * (vvv[e] + pe[c]);
            contrib += __shfl_xor(contrib, 1);
            contrib += __shfl_xor(contrib, 2);
            contrib += __shfl_xor(contrib, 4);
            contrib += __shfl_xor(contrib, 8);
            agg[c] = contrib;  // all 16 lanes of the point hold the full agg
        }
    }

    // out = Wend * agg + bend + identity; lane k writes channels 4k..4k+3
#pragma unroll
    for (int oo = 0; oo < 4; ++oo) {
        int o = k * 4 + oo;
        const float4* w4 = (const float4*)(Wend + o * CC);
        float s0 = 0.f, s1 = 0.f, s2 = 0.f, s3 = 0.f;
#pragma unroll
        for (int d = 0; d < 16; ++d) {
            float4 w = w4[d];
            s0 += w.x * agg[4 * d + 0];
            s1 += w.y * agg[4 * d + 1];
            s2 += w.z * agg[4 * d + 2];
            s3 += w.w * agg[4 * d + 3];
        }
        size_t oi = ((size_t)(b * CC + o)) * NN + n;
        out[oi] = (s0 + s1) + (s2 + s3) + bend[o] + y[oi];
    }
}

// ---------------------------------------------------------------------------
extern "C" void kernel_launch(void* const* d_in, const int* in_sizes, int n_in,
                              void* d_out, int out_size, void* d_ws, size_t ws_size,
                              hipStream_t stream) {
    const float* x    = (const float*)d_in[0];
    const float* y    = (const float*)d_in[1];
    const float* Ws   = (const float*)d_in[2];
    const float* bs   = (const float*)d_in[3];
    const float* Wk   = (const float*)d_in[4];
    const float* bk   = (const float*)d_in[5];
    const float* Wq   = (const float*)d_in[6];
    const float* bq   = (const float*)d_in[7];
    const float* P1   = (const float*)d_in[8];
    const float* pb1  = (const float*)d_in[9];
    const float* g1   = (const float*)d_in[10];
    const float* b1   = (const float*)d_in[11];
    const float* m1   = (const float*)d_in[12];
    const float* v1   = (const float*)d_in[13];
    const float* P2   = (const float*)d_in[14];
    const float* pb2  = (const float*)d_in[15];
    const float* A1   = (const float*)d_in[16];
    const float* ab1  = (const float*)d_in[17];
    const float* g2   = (const float*)d_in[18];
    const float* b2   = (const float*)d_in[19];
    const float* m2   = (const float*)d_in[20];
    const float* v2   = (const float*)d_in[21];
    const float* A2   = (const float*)d_in[22];
    const float* ab2  = (const float*)d_in[23];
    const float* Wend = (const float*)d_in[24];
    const float* bend = (const float*)d_in[25];

    float* ws    = (float*)d_ws;
    float* y1_t  = ws;                    // B*N*C = 1048576 floats
    float* key_t = ws + 1048576;          // 1048576
    float* qry_t = ws + 2097152;          // 1048576
    int*   idx   = (int*)(ws + 3145728);  // B*N*16 = 262144 ints
    float* P2T   = ws + 3407872;          // 4096
    float* A2T   = P2T + 4096;            // 16384
    float* bn1s  = A2T + 16384;
    float* bn1c  = bn1s + 64;
    float* bn2s  = bn1c + 64;
    float* bn2c  = bn2s + 256;
    float* out   = (float*)d_out;

    hipLaunchKernelGGL(prep_params, dim3(1), dim3(256), 0, stream,
                       P2, A2, g1, b1, m1, v1, g2, b2, m2, v2,
                       P2T, A2T, bn1s, bn1c, bn2s, bn2c);
    hipLaunchKernelGGL(prep_features, dim3(64), dim3(256), 0, stream,
                       x, y, Ws, bs, Wk, bk, Wq, bq, y1_t, key_t, qry_t);
    hipLaunchKernelGGL(knn_kernel, dim3(256), dim3(64), 0, stream, x, idx);
    hipLaunchKernelGGL(attn_kernel, dim3(1024), dim3(256), 0, stream,
                       x, y, y1_t, key_t, qry_t, idx,
                       P1, pb1, bn1s, bn1c, P2T, pb2,
                       A1, ab1, bn2s, bn2c, A2T, ab2,
                       Wend, bend, out);
}